// Round 1
// baseline (300.881 us; speedup 1.0000x reference)
//
#include <hip/hip_runtime.h>

#define KK 256
#define NCLS 18

// Transition on a 1-bit state encoded as t = T(0) | (T(1)<<1).
// compose2(a,b) = "apply a, then b".
__device__ __forceinline__ unsigned compose2(unsigned a, unsigned b) {
    unsigned r0 = (b >> (a & 1u)) & 1u;
    unsigned r1 = (b >> ((a >> 1) & 1u)) & 1u;
    return r0 | (r1 << 1u);
}

__global__ __launch_bounds__(64)
void proposal_suppress_kernel(const float* __restrict__ pc,   // (B,3,K)
                              const float* __restrict__ ps,   // (B,3,K)
                              const float* __restrict__ ph,   // (B,2,K)
                              const float* __restrict__ sem,  // (B,20,K)
                              const float* __restrict__ av,   // (B,K,3)
                              float* __restrict__ out)        // (B,K,28)
{
#pragma clang fp contract(off)
    const int b    = blockIdx.x;
    const int lane = threadIdx.x;

    __shared__ float s_p[KK], s_n[KK], s_d[KK][6], s_c[KK][3];

    const float* pcb  = pc  + (size_t)b * 3 * KK;
    const float* psb  = ps  + (size_t)b * 3 * KK;
    const float* phb  = ph  + (size_t)b * 2 * KK;
    const float* semb = sem + (size_t)b * (2 + NCLS) * KK;
    const float* avb  = av  + (size_t)b * KK * 3;
    float* outb       = out + (size_t)b * KK * 28;

    // lane-owned data for proposals k = 4*lane + q
    float pj[4], nj[4], dj[4][6], cj[4][3];
    unsigned Ljm = 0, Gjm = 0;   // L = p<n, G = n<p  (bit q)
    unsigned bmask = 0;          // flip state bits

#pragma unroll
    for (int q = 0; q < 4; ++q) {
        const int k = lane * 4 + q;
        const float c0 = avb[k*3+0] + pcb[0*KK + k];
        const float c1 = avb[k*3+1] + pcb[1*KK + k];
        const float c2 = avb[k*3+2] + pcb[2*KK + k];
        const float s0 = psb[0*KK + k], s1 = psb[1*KK + k], s2 = psb[2*KK + k];
        const float h0 = phb[0*KK + k], h1 = phb[1*KK + k];
        const float v0 = s0 * h1, v1 = s1, v2 = s2 * h1;
        float d[6];
        d[0] = (v0 + c0) - fabsf(s0);
        d[1] = (v0 + c0);
        d[2] = (v1 + c1) - fabsf(s1);
        d[3] = (v1 + c1);
        d[4] = (v2 + c2) - fabsf(s2);
        d[5] = (v2 + c2);
        const float p = semb[0*KK + k];
        const float n = semb[1*KK + k];

        cj[q][0] = c0; cj[q][1] = c1; cj[q][2] = c2;
#pragma unroll
        for (int m = 0; m < 6; ++m) dj[q][m] = d[m];
        pj[q] = p; nj[q] = n;
        if (p < n) Ljm |= 1u << q;
        if (n < p) Gjm |= 1u << q;

        s_p[k] = p; s_n[k] = n;
#pragma unroll
        for (int m = 0; m < 6; ++m) s_d[k][m] = d[m];
        s_c[k][0] = c0; s_c[k][1] = c1; s_c[k][2] = c2;

        // pass-through outputs
        outb[k*28 + 0] = c0; outb[k*28 + 1] = c1; outb[k*28 + 2] = c2;
        outb[k*28 + 3] = s0; outb[k*28 + 4] = s1; outb[k*28 + 5] = s2;
        outb[k*28 + 6] = h0; outb[k*28 + 7] = h1;
#pragma unroll
        for (int cc = 0; cc < NCLS; ++cc)
            outb[k*28 + 10 + cc] = semb[(2 + cc)*KK + k];
    }

    __syncthreads();

    const unsigned ID = 2u;  // identity transition: T(0)=0, T(1)=1
    for (int i = 0; i < KK - 1; ++i) {
        // broadcast row-i data (uniform LDS address -> broadcast read)
        const float piv = s_p[i], niv = s_n[i];
        const float di0 = s_d[i][0], di1 = s_d[i][1], di2 = s_d[i][2];
        const float di3 = s_d[i][3], di4 = s_d[i][4], di5 = s_d[i][5];
        const float ci0 = s_c[i][0], ci1 = s_c[i][1], ci2 = s_c[i][2];
        // scenario-A transition: b_i -> (b_i ? !G_i : L_i); handles p==n as id
        const unsigned tA = (piv < niv ? 1u : 0u) | ((niv < piv ? 0u : 1u) << 1);
        const int owner = i >> 2, slot = i & 3;

        unsigned tq[4];
        unsigned Cq = 0, cc0m = 0, cc1m = 0;
        unsigned tl = ID;
#pragma unroll
        for (int q = 0; q < 4; ++q) {
            const int j = lane * 4 + q;
            unsigned t = ID;
            if (j > i) {
                const float dx = ci0 - cj[q][0];
                const float dy = ci1 - cj[q][1];
                const float dz = ci2 - cj[q][2];
                const float dist2 = dx*dx + dy*dy + dz*dz;
                if (dist2 < 9.0f) {
                    const bool case0 = (dj[q][0] < di0) & (dj[q][1] > di1)
                                     & (dj[q][2] < di2) & (dj[q][3] > di3)
                                     & (dj[q][4] < di4) & (dj[q][5] > di5);
                    const bool case1 = (dj[q][0] > di0) & (dj[q][1] < di1)
                                     & (dj[q][2] > di2) & (dj[q][3] < di3)
                                     & (dj[q][4] > di4) & (dj[q][5] < di5);
                    if (case0) {
                        t = tA;                       // only b_i affected
                    } else if (case1) {
                        // deterministic side effect on b_j (touched once/row)
                        const unsigned bj = (bmask >> q) & 1u;
                        const unsigned nb = bj ? (((Gjm >> q) & 1u) ? 0u : 1u)
                                               : (((Ljm >> q) & 1u) ? 1u : 0u);
                        bmask = (bmask & ~(1u << q)) | (nb << q);
                    } else {
                        const bool ovx = ((dj[q][1] > di0) & (dj[q][1] < di1))
                                       | ((di1 > dj[q][0]) & (di1 < dj[q][1]));
                        const bool ovy = ((dj[q][3] > di2) & (dj[q][3] < di3))
                                       | ((di3 > dj[q][2]) & (di3 < dj[q][3]));
                        const bool ovz = ((dj[q][5] > di4) & (dj[q][5] < di5))
                                       | ((di5 > dj[q][4]) & (di5 < dj[q][5]));
                        if (ovx & ovy & ovz) {
                            // scenario C: cond(x) = second_i(x) < second_j
                            const unsigned bj = (bmask >> q) & 1u;
                            const float sj = bj ? pj[q] : nj[q];
                            const unsigned c0b = (niv < sj) ? 1u : 0u;
                            const unsigned c1b = (piv < sj) ? 1u : 0u;
                            t = c0b | ((c1b ^ 1u) << 1u);   // T(x)=x^cond(x)
                            Cq   |= 1u << q;
                            cc0m |= c0b << q;
                            cc1m |= c1b << q;
                        }
                    }
                }
            }
            tq[q] = t;
            tl = compose2(tl, t);
        }

        // skip rows with no b_i transitions and no C side effects
        const unsigned long long any = __ballot((tl != ID) || (Cq != 0));
        if (any == 0ull) continue;

        // b_i entering this row (bit `slot` of owner never modified in-row)
        const unsigned b_start =
            (((unsigned)__shfl((int)bmask, owner, 64)) >> slot) & 1u;

        // wave inclusive scan of transition composition (lane order = j order)
        unsigned incl = tl;
#pragma unroll
        for (int off = 1; off < 64; off <<= 1) {
            const unsigned other = (unsigned)__shfl_up((int)incl, (unsigned)off, 64);
            if (lane >= off) incl = compose2(other, incl);
        }
        const unsigned total = (unsigned)__shfl((int)incl, 63, 64);
        const unsigned upv   = (unsigned)__shfl_up((int)incl, 1u, 64);
        const unsigned excl  = (lane == 0) ? ID : upv;

        // evaluate C side effects with b_i at each step's entry
        unsigned cur = (excl >> b_start) & 1u;
#pragma unroll
        for (int q = 0; q < 4; ++q) {
            if ((Cq >> q) & 1u) {
                const unsigned cond = cur ? ((cc1m >> q) & 1u) : ((cc0m >> q) & 1u);
                if (!cond) bmask ^= (1u << q);   // swap_j when !(zn<fn)
            }
            cur = (tq[q] >> cur) & 1u;
        }

        // commit b_i
        if (lane == owner) {
            const unsigned nbi = (total >> b_start) & 1u;
            bmask = (bmask & ~(1u << slot)) | (nbi << slot);
        }
    }

    // write suppressed scores
#pragma unroll
    for (int q = 0; q < 4; ++q) {
        const int k = lane * 4 + q;
        const unsigned bq = (bmask >> q) & 1u;
        outb[k*28 + 8] = bq ? nj[q] : pj[q];
        outb[k*28 + 9] = bq ? pj[q] : nj[q];
    }
}

extern "C" void kernel_launch(void* const* d_in, const int* in_sizes, int n_in,
                              void* d_out, int out_size, void* d_ws, size_t ws_size,
                              hipStream_t stream) {
    const float* pc  = (const float*)d_in[0];
    const float* ps  = (const float*)d_in[1];
    const float* ph  = (const float*)d_in[2];
    const float* sem = (const float*)d_in[3];
    const float* av  = (const float*)d_in[4];
    float* out = (float*)d_out;
    const int B = in_sizes[0] / (3 * KK);
    proposal_suppress_kernel<<<dim3(B), dim3(64), 0, stream>>>(pc, ps, ph, sem, av, out);
}

// Round 2
// 96.300 us; speedup vs baseline: 3.1244x; 3.1244x over previous
//
#include <hip/hip_runtime.h>

#define KK 256
#define NCLS 18
#define MASK_BYTES_PER_BATCH (KK * KK)   // 65536

// Transition on a 1-bit state encoded as t = T(0) | (T(1)<<1).
// compose2(a,b) = "apply a, then b".  id=2, not=1, const0=0, const1=3.
__device__ __forceinline__ unsigned compose2(unsigned a, unsigned b) {
    unsigned r0 = (b >> (a & 1u)) & 1u;
    unsigned r1 = (b >> ((a >> 1) & 1u)) & 1u;
    return r0 | (r1 << 1u);
}

// ---------------------------------------------------------------------------
// Phase 1: fully parallel per-pair flag precompute.
// code byte (i,j):  bit0=A (active&case0), bit1=B (active&~case0&case1),
//                   bit2=C (active&~c0&~c1&case2),
//                   bit3=cond(0,0)=n_i<n_j  bit4=cond(1,0)=p_i<n_j
//                   bit5=cond(0,1)=n_i<p_j  bit6=cond(1,1)=p_i<p_j
// summary byte (i): bit0=row has any event, bit1=row has A or C,
//                   bit2=tA(0)=(p_i<n_i),   bit3=tA(1)=!(n_i<p_i)
// ---------------------------------------------------------------------------
__global__ __launch_bounds__(256)
void flags_kernel(const float* __restrict__ pc, const float* __restrict__ ps,
                  const float* __restrict__ ph, const float* __restrict__ sem,
                  const float* __restrict__ av,
                  unsigned char* __restrict__ ws_mask,
                  unsigned char* __restrict__ ws_sum)
{
#pragma clang fp contract(off)
    const int blk = blockIdx.x;
    const int b   = blk >> 4;
    const int g   = blk & 15;
    const int tid = threadIdx.x;

    __shared__ float sd[KK][6], sc[KK][3], sp[KK], sn[KK];
    __shared__ unsigned rowsum[16];

    const float* pcb  = pc  + (size_t)b * 3 * KK;
    const float* psb  = ps  + (size_t)b * 3 * KK;
    const float* phb  = ph  + (size_t)b * 2 * KK;
    const float* semb = sem + (size_t)b * (2 + NCLS) * KK;
    const float* avb  = av  + (size_t)b * KK * 3;

    {   // stage proposal `tid`'s derived data (identical float exprs to ref)
        const int k = tid;
        const float c0 = avb[k*3+0] + pcb[0*KK + k];
        const float c1 = avb[k*3+1] + pcb[1*KK + k];
        const float c2 = avb[k*3+2] + pcb[2*KK + k];
        const float s0 = psb[0*KK + k], s1 = psb[1*KK + k], s2 = psb[2*KK + k];
        const float h1 = phb[1*KK + k];
        const float v0 = s0 * h1, v1 = s1, v2 = s2 * h1;
        sd[k][0] = (v0 + c0) - fabsf(s0);
        sd[k][1] = (v0 + c0);
        sd[k][2] = (v1 + c1) - fabsf(s1);
        sd[k][3] = (v1 + c1);
        sd[k][4] = (v2 + c2) - fabsf(s2);
        sd[k][5] = (v2 + c2);
        sc[k][0] = c0; sc[k][1] = c1; sc[k][2] = c2;
        sp[k] = semb[0*KK + k];
        sn[k] = semb[1*KK + k];
    }
    if (tid < 16) rowsum[tid] = 0;
    __syncthreads();

    const int rl = tid >> 4;          // local row 0..15
    const int i  = g * 16 + rl;       // global row
    const int j0 = (tid & 15) * 16;   // 16 j's per thread

    const float piv = sp[i], niv = sn[i];
    const float di0 = sd[i][0], di1 = sd[i][1], di2 = sd[i][2];
    const float di3 = sd[i][3], di4 = sd[i][4], di5 = sd[i][5];
    const float ci0 = sc[i][0], ci1 = sc[i][1], ci2 = sc[i][2];

    unsigned codes[16];
    unsigned anyf = 0, acf = 0;
#pragma unroll
    for (int t = 0; t < 16; ++t) {
        const int j = j0 + t;
        unsigned code = 0;
        if (j > i) {
            const float dx = ci0 - sc[j][0];
            const float dy = ci1 - sc[j][1];
            const float dz = ci2 - sc[j][2];
            const float dist2 = dx*dx + dy*dy + dz*dz;
            if (dist2 < 9.0f) {
                const float e0 = sd[j][0], e1 = sd[j][1], e2 = sd[j][2];
                const float e3 = sd[j][3], e4 = sd[j][4], e5 = sd[j][5];
                const bool case0 = (e0 < di0) & (e1 > di1) & (e2 < di2)
                                 & (e3 > di3) & (e4 < di4) & (e5 > di5);
                const bool case1 = (e0 > di0) & (e1 < di1) & (e2 > di2)
                                 & (e3 < di3) & (e4 > di4) & (e5 < di5);
                if (case0) {
                    code = 1u;
                } else if (case1) {
                    code = 2u;
                } else {
                    const bool ovx = ((e1 > di0) & (e1 < di1)) | ((di1 > e0) & (di1 < e1));
                    const bool ovy = ((e3 > di2) & (e3 < di3)) | ((di3 > e2) & (di3 < e3));
                    const bool ovz = ((e5 > di4) & (e5 < di5)) | ((di5 > e4) & (di5 < e5));
                    if (ovx & ovy & ovz) {
                        const float pj = sp[j], nj = sn[j];
                        const unsigned c00 = (niv < nj) ? 1u : 0u;
                        const unsigned c10 = (piv < nj) ? 1u : 0u;
                        const unsigned c01 = (niv < pj) ? 1u : 0u;
                        const unsigned c11 = (piv < pj) ? 1u : 0u;
                        code = 4u | (c00<<3) | (c10<<4) | (c01<<5) | (c11<<6);
                    }
                }
            }
        }
        codes[t] = code;
        anyf |= code;
        acf  |= code & 5u;
    }

    // pack 16 codes -> 4 words -> one 16B store
    uint4 w;
    w.x = codes[0]  | (codes[1]<<8)  | (codes[2]<<16)  | (codes[3]<<24);
    w.y = codes[4]  | (codes[5]<<8)  | (codes[6]<<16)  | (codes[7]<<24);
    w.z = codes[8]  | (codes[9]<<8)  | (codes[10]<<16) | (codes[11]<<24);
    w.w = codes[12] | (codes[13]<<8) | (codes[14]<<16) | (codes[15]<<24);
    *(uint4*)(ws_mask + (size_t)b * MASK_BYTES_PER_BATCH + i * KK + j0) = w;

    const unsigned f = (anyf ? 1u : 0u) | (acf ? 2u : 0u);
    if (f) atomicOr(&rowsum[rl], f);
    __syncthreads();

    if (tid < 16) {
        const int i2 = g * 16 + tid;
        const unsigned tab = ((sp[i2] < sn[i2]) ? 4u : 0u)
                           | ((sn[i2] < sp[i2]) ? 0u : 8u);
        ws_sum[b * KK + i2] = (unsigned char)(rowsum[tid] | tab);
    }
}

// ---------------------------------------------------------------------------
// Phase 2: one wave per batch, serial over rows, ballot-based 1-bit scan.
// ---------------------------------------------------------------------------
__global__ __launch_bounds__(64)
void suppress2_kernel(const float* __restrict__ ph, const float* __restrict__ pc,
                      const float* __restrict__ ps, const float* __restrict__ sem,
                      const float* __restrict__ av,
                      const unsigned char* __restrict__ ws_mask,
                      const unsigned char* __restrict__ ws_sum,
                      float* __restrict__ out)
{
    const int b    = blockIdx.x;
    const int lane = threadIdx.x;

    __shared__ unsigned s_mask[KK * 64];   // 64 KB: linear copy of batch codes

    const float* pcb  = pc  + (size_t)b * 3 * KK;
    const float* psb  = ps  + (size_t)b * 3 * KK;
    const float* phb  = ph  + (size_t)b * 2 * KK;
    const float* semb = sem + (size_t)b * (2 + NCLS) * KK;
    const float* avb  = av  + (size_t)b * KK * 3;
    float* outb       = out + (size_t)b * KK * 28;

    // stage codes: global -> LDS, 8 x 16B in flight per sweep group
    const uint4* gm = (const uint4*)(ws_mask + (size_t)b * MASK_BYTES_PER_BATCH);
    uint4* sm4 = (uint4*)s_mask;
    for (int so = 0; so < 64; so += 8) {
        uint4 v[8];
#pragma unroll
        for (int t = 0; t < 8; ++t) v[t] = gm[(so + t) * 64 + lane];
#pragma unroll
        for (int t = 0; t < 8; ++t) sm4[(so + t) * 64 + lane] = v[t];
    }

    float pj[4], nj[4];
    unsigned Ljm = 0, Gjm = 0, bmask = 0;

#pragma unroll
    for (int q = 0; q < 4; ++q) {
        const int k = lane * 4 + q;
        const float c0 = avb[k*3+0] + pcb[0*KK + k];
        const float c1 = avb[k*3+1] + pcb[1*KK + k];
        const float c2 = avb[k*3+2] + pcb[2*KK + k];
        const float s0 = psb[0*KK + k], s1 = psb[1*KK + k], s2 = psb[2*KK + k];
        const float h0 = phb[0*KK + k], h1 = phb[1*KK + k];
        const float p = semb[0*KK + k];
        const float n = semb[1*KK + k];
        pj[q] = p; nj[q] = n;
        if (p < n) Ljm |= 1u << q;
        if (n < p) Gjm |= 1u << q;

        outb[k*28 + 0] = c0; outb[k*28 + 1] = c1; outb[k*28 + 2] = c2;
        outb[k*28 + 3] = s0; outb[k*28 + 4] = s1; outb[k*28 + 5] = s2;
        outb[k*28 + 6] = h0; outb[k*28 + 7] = h1;
#pragma unroll
        for (int cc = 0; cc < NCLS; ++cc)
            outb[k*28 + 10 + cc] = semb[(2 + cc)*KK + k];
    }

    // summary bytes -> uniform bitmaps via ballots
    const unsigned char* sb = ws_sum + b * KK;
    const unsigned sb0 = sb[lane], sb1 = sb[64 + lane],
                   sb2 = sb[128 + lane], sb3 = sb[192 + lane];
    const unsigned long long any0 = __ballot(sb0 & 1u), ac0 = __ballot(sb0 & 2u),
                             a0_0 = __ballot(sb0 & 4u), a1_0 = __ballot(sb0 & 8u);
    const unsigned long long any1 = __ballot(sb1 & 1u), ac1 = __ballot(sb1 & 2u),
                             a0_1 = __ballot(sb1 & 4u), a1_1 = __ballot(sb1 & 8u);
    const unsigned long long any2 = __ballot(sb2 & 1u), ac2 = __ballot(sb2 & 2u),
                             a0_2 = __ballot(sb2 & 4u), a1_2 = __ballot(sb2 & 8u);
    const unsigned long long any3 = __ballot(sb3 & 1u), ac3 = __ballot(sb3 & 2u),
                             a0_3 = __ballot(sb3 & 4u), a1_3 = __ballot(sb3 & 8u);

    __syncthreads();   // LDS mask copy visible (single wave: orders ds ops)

    const unsigned long long below = (1ull << lane) - 1ull;

#define APPLY_B(q) { if ((m >> (8*(q)+1)) & 1u) { \
        const unsigned bj = (bmask >> (q)) & 1u; \
        const unsigned nb = bj ? (((Gjm >> (q)) & 1u) ^ 1u) : ((Ljm >> (q)) & 1u); \
        bmask = (bmask & ~(1u << (q))) | (nb << (q)); } }

#define DOQ(q, TQ) { \
        const unsigned code = (m >> (8*(q))) & 0x7fu; \
        unsigned t = 2u; \
        if (code & 1u) { t = tA; } \
        else if (code & 2u) { \
            const unsigned bj = (bmask >> (q)) & 1u; \
            const unsigned nb = bj ? (((Gjm >> (q)) & 1u) ^ 1u) : ((Ljm >> (q)) & 1u); \
            bmask = (bmask & ~(1u << (q))) | (nb << (q)); \
        } else if (code & 4u) { \
            const unsigned bj = (bmask >> (q)) & 1u; \
            const unsigned c0 = (code >> (bj ? 5 : 3)) & 1u; \
            const unsigned c1 = (code >> (bj ? 6 : 4)) & 1u; \
            t = c0 | ((c1 ^ 1u) << 1); \
            Cq |= 1u << (q); cc0m |= c0 << (q); cc1m |= c1 << (q); \
        } \
        TQ = t; tl = compose2(tl, t); }

#define SEQ(q, TQ) { \
        if ((Cq >> (q)) & 1u) { \
            const unsigned cond = cur ? ((cc1m >> (q)) & 1u) : ((cc0m >> (q)) & 1u); \
            if (!cond) bmask ^= (1u << (q)); \
        } \
        cur = (TQ >> cur) & 1u; }

#define RUNCHUNK(W, ANY, AC, A0, A1, NROWS) \
    for (int bb = 0; bb < (NROWS); ++bb) { \
        if (!((ANY >> bb) & 1ull)) continue; \
        const int i = ((W) << 6) + bb; \
        const unsigned m = s_mask[i * 64 + lane]; \
        if (!((AC >> bb) & 1ull)) { APPLY_B(0) APPLY_B(1) APPLY_B(2) APPLY_B(3) continue; } \
        const unsigned tA = ((unsigned)(A0 >> bb) & 1u) | (((unsigned)(A1 >> bb) & 1u) << 1); \
        const int owner = i >> 2, slot = i & 3; \
        unsigned tq0, tq1, tq2, tq3, Cq = 0, cc0m = 0, cc1m = 0, tl = 2u; \
        DOQ(0, tq0) DOQ(1, tq1) DOQ(2, tq2) DOQ(3, tq3) \
        const unsigned long long bsb = __ballot(((bmask >> slot) & 1u) != 0u); \
        const unsigned b_start = (unsigned)(bsb >> owner) & 1u; \
        const unsigned long long cmask = __ballot(tl == 0u || tl == 3u); \
        const unsigned long long vmask = __ballot(tl == 3u); \
        const unsigned long long nmask = __ballot(tl == 1u); \
        unsigned excl; \
        const unsigned long long cb = cmask & below; \
        if (cb) { \
            const int k = 63 - __builtin_clzll(cb); \
            const unsigned long long abv = below & ~((2ull << k) - 1ull); \
            excl = ((unsigned)(vmask >> k) & 1u) \
                 ^ ((unsigned)__builtin_popcountll(nmask & abv) & 1u); \
        } else { \
            excl = b_start ^ ((unsigned)__builtin_popcountll(nmask & below) & 1u); \
        } \
        unsigned bfin; \
        if (cmask) { \
            const int k = 63 - __builtin_clzll(cmask); \
            const unsigned long long abv2 = ~((2ull << k) - 1ull); \
            bfin = ((unsigned)(vmask >> k) & 1u) \
                 ^ ((unsigned)__builtin_popcountll(nmask & abv2) & 1u); \
        } else { \
            bfin = b_start ^ ((unsigned)__builtin_popcountll(nmask) & 1u); \
        } \
        unsigned cur = excl; \
        SEQ(0, tq0) SEQ(1, tq1) SEQ(2, tq2) SEQ(3, tq3) \
        if (lane == owner) bmask = (bmask & ~(1u << slot)) | (bfin << slot); \
    }

    RUNCHUNK(0, any0, ac0, a0_0, a1_0, 64)
    RUNCHUNK(1, any1, ac1, a0_1, a1_1, 64)
    RUNCHUNK(2, any2, ac2, a0_2, a1_2, 64)
    RUNCHUNK(3, any3, ac3, a0_3, a1_3, 63)

#undef RUNCHUNK
#undef SEQ
#undef DOQ
#undef APPLY_B

#pragma unroll
    for (int q = 0; q < 4; ++q) {
        const int k = lane * 4 + q;
        const unsigned bq = (bmask >> q) & 1u;
        outb[k*28 + 8] = bq ? nj[q] : pj[q];
        outb[k*28 + 9] = bq ? pj[q] : nj[q];
    }
}

// ---------------------------------------------------------------------------
// Fallback (round-1 verified kernel) in case ws_size is too small.
// ---------------------------------------------------------------------------
__global__ __launch_bounds__(64)
void proposal_suppress_kernel(const float* __restrict__ pc, const float* __restrict__ ps,
                              const float* __restrict__ ph, const float* __restrict__ sem,
                              const float* __restrict__ av, float* __restrict__ out)
{
#pragma clang fp contract(off)
    const int b    = blockIdx.x;
    const int lane = threadIdx.x;

    __shared__ float s_p[KK], s_n[KK], s_d[KK][6], s_c[KK][3];

    const float* pcb  = pc  + (size_t)b * 3 * KK;
    const float* psb  = ps  + (size_t)b * 3 * KK;
    const float* phb  = ph  + (size_t)b * 2 * KK;
    const float* semb = sem + (size_t)b * (2 + NCLS) * KK;
    const float* avb  = av  + (size_t)b * KK * 3;
    float* outb       = out + (size_t)b * KK * 28;

    float pj[4], nj[4], dj[4][6], cj[4][3];
    unsigned Ljm = 0, Gjm = 0, bmask = 0;

#pragma unroll
    for (int q = 0; q < 4; ++q) {
        const int k = lane * 4 + q;
        const float c0 = avb[k*3+0] + pcb[0*KK + k];
        const float c1 = avb[k*3+1] + pcb[1*KK + k];
        const float c2 = avb[k*3+2] + pcb[2*KK + k];
        const float s0 = psb[0*KK + k], s1 = psb[1*KK + k], s2 = psb[2*KK + k];
        const float h0 = phb[0*KK + k], h1 = phb[1*KK + k];
        const float v0 = s0 * h1, v1 = s1, v2 = s2 * h1;
        float d[6];
        d[0] = (v0 + c0) - fabsf(s0); d[1] = (v0 + c0);
        d[2] = (v1 + c1) - fabsf(s1); d[3] = (v1 + c1);
        d[4] = (v2 + c2) - fabsf(s2); d[5] = (v2 + c2);
        const float p = semb[0*KK + k];
        const float n = semb[1*KK + k];
        cj[q][0] = c0; cj[q][1] = c1; cj[q][2] = c2;
#pragma unroll
        for (int m = 0; m < 6; ++m) dj[q][m] = d[m];
        pj[q] = p; nj[q] = n;
        if (p < n) Ljm |= 1u << q;
        if (n < p) Gjm |= 1u << q;
        s_p[k] = p; s_n[k] = n;
#pragma unroll
        for (int m = 0; m < 6; ++m) s_d[k][m] = d[m];
        s_c[k][0] = c0; s_c[k][1] = c1; s_c[k][2] = c2;
        outb[k*28 + 0] = c0; outb[k*28 + 1] = c1; outb[k*28 + 2] = c2;
        outb[k*28 + 3] = s0; outb[k*28 + 4] = s1; outb[k*28 + 5] = s2;
        outb[k*28 + 6] = h0; outb[k*28 + 7] = h1;
#pragma unroll
        for (int cc = 0; cc < NCLS; ++cc)
            outb[k*28 + 10 + cc] = semb[(2 + cc)*KK + k];
    }
    __syncthreads();

    const unsigned ID = 2u;
    for (int i = 0; i < KK - 1; ++i) {
        const float piv = s_p[i], niv = s_n[i];
        const float di0 = s_d[i][0], di1 = s_d[i][1], di2 = s_d[i][2];
        const float di3 = s_d[i][3], di4 = s_d[i][4], di5 = s_d[i][5];
        const float ci0 = s_c[i][0], ci1 = s_c[i][1], ci2 = s_c[i][2];
        const unsigned tA = (piv < niv ? 1u : 0u) | ((niv < piv ? 0u : 1u) << 1);
        const int owner = i >> 2, slot = i & 3;

        unsigned tq[4];
        unsigned Cq = 0, cc0m = 0, cc1m = 0;
        unsigned tl = ID;
#pragma unroll
        for (int q = 0; q < 4; ++q) {
            const int j = lane * 4 + q;
            unsigned t = ID;
            if (j > i) {
                const float dx = ci0 - cj[q][0];
                const float dy = ci1 - cj[q][1];
                const float dz = ci2 - cj[q][2];
                const float dist2 = dx*dx + dy*dy + dz*dz;
                if (dist2 < 9.0f) {
                    const bool case0 = (dj[q][0] < di0) & (dj[q][1] > di1)
                                     & (dj[q][2] < di2) & (dj[q][3] > di3)
                                     & (dj[q][4] < di4) & (dj[q][5] > di5);
                    const bool case1 = (dj[q][0] > di0) & (dj[q][1] < di1)
                                     & (dj[q][2] > di2) & (dj[q][3] < di3)
                                     & (dj[q][4] > di4) & (dj[q][5] < di5);
                    if (case0) {
                        t = tA;
                    } else if (case1) {
                        const unsigned bj = (bmask >> q) & 1u;
                        const unsigned nb = bj ? (((Gjm >> q) & 1u) ? 0u : 1u)
                                               : (((Ljm >> q) & 1u) ? 1u : 0u);
                        bmask = (bmask & ~(1u << q)) | (nb << q);
                    } else {
                        const bool ovx = ((dj[q][1] > di0) & (dj[q][1] < di1))
                                       | ((di1 > dj[q][0]) & (di1 < dj[q][1]));
                        const bool ovy = ((dj[q][3] > di2) & (dj[q][3] < di3))
                                       | ((di3 > dj[q][2]) & (di3 < dj[q][3]));
                        const bool ovz = ((dj[q][5] > di4) & (dj[q][5] < di5))
                                       | ((di5 > dj[q][4]) & (di5 < dj[q][5]));
                        if (ovx & ovy & ovz) {
                            const unsigned bj = (bmask >> q) & 1u;
                            const float sj = bj ? pj[q] : nj[q];
                            const unsigned c0b = (niv < sj) ? 1u : 0u;
                            const unsigned c1b = (piv < sj) ? 1u : 0u;
                            t = c0b | ((c1b ^ 1u) << 1u);
                            Cq |= 1u << q; cc0m |= c0b << q; cc1m |= c1b << q;
                        }
                    }
                }
            }
            tq[q] = t;
            tl = compose2(tl, t);
        }

        const unsigned long long any = __ballot((tl != ID) || (Cq != 0));
        if (any == 0ull) continue;

        const unsigned b_start = (((unsigned)__shfl((int)bmask, owner, 64)) >> slot) & 1u;

        unsigned incl = tl;
#pragma unroll
        for (int off = 1; off < 64; off <<= 1) {
            const unsigned other = (unsigned)__shfl_up((int)incl, (unsigned)off, 64);
            if (lane >= off) incl = compose2(other, incl);
        }
        const unsigned total = (unsigned)__shfl((int)incl, 63, 64);
        const unsigned upv   = (unsigned)__shfl_up((int)incl, 1u, 64);
        const unsigned excl  = (lane == 0) ? ID : upv;

        unsigned cur = (excl >> b_start) & 1u;
#pragma unroll
        for (int q = 0; q < 4; ++q) {
            if ((Cq >> q) & 1u) {
                const unsigned cond = cur ? ((cc1m >> q) & 1u) : ((cc0m >> q) & 1u);
                if (!cond) bmask ^= (1u << q);
            }
            cur = (tq[q] >> cur) & 1u;
        }
        if (lane == owner) {
            const unsigned nbi = (total >> b_start) & 1u;
            bmask = (bmask & ~(1u << slot)) | (nbi << slot);
        }
    }

#pragma unroll
    for (int q = 0; q < 4; ++q) {
        const int k = lane * 4 + q;
        const unsigned bq = (bmask >> q) & 1u;
        outb[k*28 + 8] = bq ? nj[q] : pj[q];
        outb[k*28 + 9] = bq ? pj[q] : nj[q];
    }
}

extern "C" void kernel_launch(void* const* d_in, const int* in_sizes, int n_in,
                              void* d_out, int out_size, void* d_ws, size_t ws_size,
                              hipStream_t stream) {
    const float* pc  = (const float*)d_in[0];
    const float* ps  = (const float*)d_in[1];
    const float* ph  = (const float*)d_in[2];
    const float* sem = (const float*)d_in[3];
    const float* av  = (const float*)d_in[4];
    float* out = (float*)d_out;
    const int B = in_sizes[0] / (3 * KK);

    const size_t need = (size_t)B * MASK_BYTES_PER_BATCH + (size_t)B * KK;
    if (ws_size >= need) {
        unsigned char* wm   = (unsigned char*)d_ws;
        unsigned char* wsum = wm + (size_t)B * MASK_BYTES_PER_BATCH;
        flags_kernel<<<dim3(B * 16), dim3(256), 0, stream>>>(pc, ps, ph, sem, av, wm, wsum);
        suppress2_kernel<<<dim3(B), dim3(64), 0, stream>>>(ph, pc, ps, sem, av, wm, wsum, out);
    } else {
        proposal_suppress_kernel<<<dim3(B), dim3(64), 0, stream>>>(pc, ps, ph, sem, av, out);
    }
}

// Round 3
// 64.061 us; speedup vs baseline: 4.6968x; 1.5033x over previous
//
#include <hip/hip_runtime.h>

#define KK 256
#define NCLS 18
#define MASK_BYTES_PER_BATCH (KK * KK)   // 65536

// Transition on a 1-bit state encoded as t = T(0) | (T(1)<<1).
// compose2(a,b) = "apply a, then b".  id=2, not=1, const0=0, const1=3.
__device__ __forceinline__ unsigned compose2(unsigned a, unsigned b) {
    unsigned r0 = (b >> (a & 1u)) & 1u;
    unsigned r1 = (b >> ((a >> 1) & 1u)) & 1u;
    return r0 | (r1 << 1u);
}

// ---------------------------------------------------------------------------
// Phase 1: fully parallel per-pair flag precompute + all pass-through outputs.
// code byte (i,j):  bit0=A, bit1=B, bit2=C,
//                   bit3=cond(0,0)=n_i<n_j  bit4=cond(1,0)=p_i<n_j
//                   bit5=cond(0,1)=n_i<p_j  bit6=cond(1,1)=p_i<p_j
// summary byte (i): bit0=row has any event, bit1=row has A or C,
//                   bit2=tA(0)=(p_i<n_i),   bit3=tA(1)=!(n_i<p_i)
// ---------------------------------------------------------------------------
__global__ __launch_bounds__(256)
void flags_kernel(const float* __restrict__ pc, const float* __restrict__ ps,
                  const float* __restrict__ ph, const float* __restrict__ sem,
                  const float* __restrict__ av,
                  unsigned char* __restrict__ ws_mask,
                  unsigned char* __restrict__ ws_sum,
                  float* __restrict__ out)
{
#pragma clang fp contract(off)
    const int blk = blockIdx.x;
    const int b   = blk >> 4;
    const int g   = blk & 15;
    const int tid = threadIdx.x;

    __shared__ float sd[KK][6], sc[KK][3], sp[KK], sn[KK];
    __shared__ unsigned rowsum[16];

    const float* pcb  = pc  + (size_t)b * 3 * KK;
    const float* psb  = ps  + (size_t)b * 3 * KK;
    const float* phb  = ph  + (size_t)b * 2 * KK;
    const float* semb = sem + (size_t)b * (2 + NCLS) * KK;
    const float* avb  = av  + (size_t)b * KK * 3;
    float* outb       = out + (size_t)b * KK * 28;

    {   // stage proposal `tid`'s derived data (identical float exprs to ref)
        const int k = tid;
        const float c0 = avb[k*3+0] + pcb[0*KK + k];
        const float c1 = avb[k*3+1] + pcb[1*KK + k];
        const float c2 = avb[k*3+2] + pcb[2*KK + k];
        const float s0 = psb[0*KK + k], s1 = psb[1*KK + k], s2 = psb[2*KK + k];
        const float h1 = phb[1*KK + k];
        const float v0 = s0 * h1, v1 = s1, v2 = s2 * h1;
        sd[k][0] = (v0 + c0) - fabsf(s0);
        sd[k][1] = (v0 + c0);
        sd[k][2] = (v1 + c1) - fabsf(s1);
        sd[k][3] = (v1 + c1);
        sd[k][4] = (v2 + c2) - fabsf(s2);
        sd[k][5] = (v2 + c2);
        sc[k][0] = c0; sc[k][1] = c1; sc[k][2] = c2;
        sp[k] = semb[0*KK + k];
        sn[k] = semb[1*KK + k];
    }
    if (tid < 16) rowsum[tid] = 0;
    __syncthreads();

    const int rl = tid >> 4;          // local row 0..15
    const int i  = g * 16 + rl;       // global row
    const int j0 = (tid & 15) * 16;   // 16 j's per thread

    const float piv = sp[i], niv = sn[i];
    const float di0 = sd[i][0], di1 = sd[i][1], di2 = sd[i][2];
    const float di3 = sd[i][3], di4 = sd[i][4], di5 = sd[i][5];
    const float ci0 = sc[i][0], ci1 = sc[i][1], ci2 = sc[i][2];

    unsigned codes[16];
    unsigned anyf = 0, acf = 0;
#pragma unroll
    for (int t = 0; t < 16; ++t) {
        const int j = j0 + t;
        unsigned code = 0;
        if (j > i) {
            const float dx = ci0 - sc[j][0];
            const float dy = ci1 - sc[j][1];
            const float dz = ci2 - sc[j][2];
            const float dist2 = dx*dx + dy*dy + dz*dz;
            if (dist2 < 9.0f) {
                const float e0 = sd[j][0], e1 = sd[j][1], e2 = sd[j][2];
                const float e3 = sd[j][3], e4 = sd[j][4], e5 = sd[j][5];
                const bool case0 = (e0 < di0) & (e1 > di1) & (e2 < di2)
                                 & (e3 > di3) & (e4 < di4) & (e5 > di5);
                const bool case1 = (e0 > di0) & (e1 < di1) & (e2 > di2)
                                 & (e3 < di3) & (e4 > di4) & (e5 < di5);
                if (case0) {
                    code = 1u;
                } else if (case1) {
                    code = 2u;
                } else {
                    const bool ovx = ((e1 > di0) & (e1 < di1)) | ((di1 > e0) & (di1 < e1));
                    const bool ovy = ((e3 > di2) & (e3 < di3)) | ((di3 > e2) & (di3 < e3));
                    const bool ovz = ((e5 > di4) & (e5 < di5)) | ((di5 > e4) & (di5 < e5));
                    if (ovx & ovy & ovz) {
                        const float pj = sp[j], nj = sn[j];
                        const unsigned c00 = (niv < nj) ? 1u : 0u;
                        const unsigned c10 = (piv < nj) ? 1u : 0u;
                        const unsigned c01 = (niv < pj) ? 1u : 0u;
                        const unsigned c11 = (piv < pj) ? 1u : 0u;
                        code = 4u | (c00<<3) | (c10<<4) | (c01<<5) | (c11<<6);
                    }
                }
            }
        }
        codes[t] = code;
        anyf |= code;
        acf  |= code & 5u;
    }

    // pack 16 codes -> 4 words -> one 16B store
    uint4 w;
    w.x = codes[0]  | (codes[1]<<8)  | (codes[2]<<16)  | (codes[3]<<24);
    w.y = codes[4]  | (codes[5]<<8)  | (codes[6]<<16)  | (codes[7]<<24);
    w.z = codes[8]  | (codes[9]<<8)  | (codes[10]<<16) | (codes[11]<<24);
    w.w = codes[12] | (codes[13]<<8) | (codes[14]<<16) | (codes[15]<<24);
    *(uint4*)(ws_mask + (size_t)b * MASK_BYTES_PER_BATCH + i * KK + j0) = w;

    const unsigned f = (anyf ? 1u : 0u) | (acf ? 2u : 0u);
    if (f) atomicOr(&rowsum[rl], f);

    // pass-through outputs for this block's k-slice [g*16, g*16+16)
    for (int s = tid; s < 16 * 28; s += 256) {
        const int kk = g * 16 + (s / 28);
        const int c  = s % 28;
        if (c == 8 || c == 9) continue;      // scores written by phase 2
        float val;
        if (c < 3)       val = sc[kk][c];
        else if (c < 6)  val = psb[(c - 3) * KK + kk];
        else if (c < 8)  val = phb[(c - 6) * KK + kk];
        else             val = semb[(c - 8) * KK + kk];
        outb[(size_t)kk * 28 + c] = val;
    }

    __syncthreads();
    if (tid < 16) {
        const int i2 = g * 16 + tid;
        const unsigned tab = ((sp[i2] < sn[i2]) ? 4u : 0u)
                           | ((sn[i2] < sp[i2]) ? 0u : 8u);
        ws_sum[b * KK + i2] = (unsigned char)(rowsum[tid] | tab);
    }
}

// ---------------------------------------------------------------------------
// Phase 2: one wave per batch, serial over rows, ballot-based 1-bit scan.
// Prefetched row codes, hoisted b_start ballot, branchless DOQ, tree compose.
// ---------------------------------------------------------------------------
__global__ __launch_bounds__(64)
void suppress3_kernel(const float* __restrict__ sem,
                      const unsigned char* __restrict__ ws_mask,
                      const unsigned char* __restrict__ ws_sum,
                      float* __restrict__ out)
{
    const int b    = blockIdx.x;
    const int lane = threadIdx.x;

    __shared__ unsigned s_mask[KK * 64];   // 64 KB: linear copy of batch codes

    const float* semb = sem + (size_t)b * (2 + NCLS) * KK;
    float* outb       = out + (size_t)b * KK * 28;

    // stage codes: global -> LDS, 8 x 16B in flight per sweep group
    const uint4* gm = (const uint4*)(ws_mask + (size_t)b * MASK_BYTES_PER_BATCH);
    uint4* sm4 = (uint4*)s_mask;
    for (int so = 0; so < 64; so += 8) {
        uint4 v[8];
#pragma unroll
        for (int t = 0; t < 8; ++t) v[t] = gm[(so + t) * 64 + lane];
#pragma unroll
        for (int t = 0; t < 8; ++t) sm4[(so + t) * 64 + lane] = v[t];
    }

    float pj[4], nj[4];
    unsigned Ljm = 0, Gjm = 0, bmask = 0;
#pragma unroll
    for (int q = 0; q < 4; ++q) {
        const int k = lane * 4 + q;
        const float p = semb[0*KK + k];
        const float n = semb[1*KK + k];
        pj[q] = p; nj[q] = n;
        if (p < n) Ljm |= 1u << q;
        if (n < p) Gjm |= 1u << q;
    }

    // summary bytes -> uniform bitmaps via ballots
    const unsigned char* sb = ws_sum + b * KK;
    const unsigned sb0 = sb[lane], sb1 = sb[64 + lane],
                   sb2 = sb[128 + lane], sb3 = sb[192 + lane];
    const unsigned long long any0 = __ballot(sb0 & 1u), ac0 = __ballot(sb0 & 2u),
                             a0_0 = __ballot(sb0 & 4u), a1_0 = __ballot(sb0 & 8u);
    const unsigned long long any1 = __ballot(sb1 & 1u), ac1 = __ballot(sb1 & 2u),
                             a0_1 = __ballot(sb1 & 4u), a1_1 = __ballot(sb1 & 8u);
    const unsigned long long any2 = __ballot(sb2 & 1u), ac2 = __ballot(sb2 & 2u),
                             a0_2 = __ballot(sb2 & 4u), a1_2 = __ballot(sb2 & 8u);
    const unsigned long long any3 = __ballot(sb3 & 1u), ac3 = __ballot(sb3 & 2u),
                             a0_3 = __ballot(sb3 & 4u), a1_3 = __ballot(sb3 & 8u);

    __syncthreads();   // staging complete

    const unsigned long long below = (1ull << lane) - 1ull;

#define APPLY_B(q) { \
        const unsigned isB = (m >> (8*(q)+1)) & 1u; \
        const unsigned bj  = (bmask >> (q)) & 1u; \
        const unsigned nb  = bj ? (((Gjm >> (q)) & 1u) ^ 1u) : ((Ljm >> (q)) & 1u); \
        const unsigned nv  = (bmask & ~(1u << (q))) | (nb << (q)); \
        bmask = isB ? nv : bmask; }

#define DOQ(q, TQ) { \
        const unsigned code = (m >> (8*(q))) & 0xffu; \
        const unsigned isA = code & 1u; \
        const unsigned isB = (code >> 1) & 1u; \
        const unsigned isC = (code >> 2) & 1u; \
        const unsigned bj  = (bmask >> (q)) & 1u; \
        const unsigned nb  = bj ? (((Gjm >> (q)) & 1u) ^ 1u) : ((Ljm >> (q)) & 1u); \
        const unsigned nv  = (bmask & ~(1u << (q))) | (nb << (q)); \
        bmask = isB ? nv : bmask; \
        const unsigned sh = bj ? 5u : 3u; \
        const unsigned c0 = (code >> sh) & 1u; \
        const unsigned c1 = (code >> (sh + 1u)) & 1u; \
        const unsigned tC = c0 | ((c1 ^ 1u) << 1); \
        TQ = isA ? tA : (isC ? tC : 2u); \
        Cq   |= isC << (q); \
        cc0m |= (isC & c0) << (q); \
        cc1m |= (isC & c1) << (q); }

#define SEQ(q, TQ) { \
        if ((Cq >> (q)) & 1u) { \
            const unsigned cond = cur ? ((cc1m >> (q)) & 1u) : ((cc0m >> (q)) & 1u); \
            if (!cond) bmask ^= (1u << (q)); \
        } \
        cur = (TQ >> cur) & 1u; }

#define RUNCHUNK(W, ANY, AC, A0, A1, NROWS) \
    for (int bb = 0; bb < (NROWS); ++bb) { \
        const int i = ((W) << 6) + bb; \
        const unsigned mnext = s_mask[(i + 1) * 64 + lane]; \
        if (((ANY) >> bb) & 1ull) { \
            const unsigned m = mcur; \
            if (!(((AC) >> bb) & 1ull)) { \
                APPLY_B(0) APPLY_B(1) APPLY_B(2) APPLY_B(3) \
            } else { \
                const int owner = i >> 2, slot = i & 3; \
                const unsigned long long bsb = __ballot(((bmask >> slot) & 1u) != 0u); \
                const unsigned b_start = (unsigned)(bsb >> owner) & 1u; \
                const unsigned tA = ((unsigned)((A0) >> bb) & 1u) \
                                  | (((unsigned)((A1) >> bb) & 1u) << 1); \
                unsigned tq0, tq1, tq2, tq3, Cq = 0, cc0m = 0, cc1m = 0; \
                DOQ(0, tq0) DOQ(1, tq1) DOQ(2, tq2) DOQ(3, tq3) \
                const unsigned tl = compose2(compose2(tq0, tq1), compose2(tq2, tq3)); \
                const unsigned long long b0m = __ballot(tl & 1u); \
                const unsigned long long b1m = __ballot(tl & 2u); \
                const unsigned long long nmask = b0m & ~b1m; \
                const unsigned long long vmask = b0m &  b1m; \
                const unsigned long long cmask = ~(b0m ^ b1m); \
                unsigned excl; \
                const unsigned long long cb = cmask & below; \
                if (cb) { \
                    const int k = 63 - __builtin_clzll(cb); \
                    const unsigned long long abv = below & ~((2ull << k) - 1ull); \
                    excl = ((unsigned)(vmask >> k) & 1u) \
                         ^ ((unsigned)__builtin_popcountll(nmask & abv) & 1u); \
                } else { \
                    excl = b_start ^ ((unsigned)__builtin_popcountll(nmask & below) & 1u); \
                } \
                unsigned bfin; \
                if (cmask) { \
                    const int k = 63 - __builtin_clzll(cmask); \
                    const unsigned long long abv2 = ~((2ull << k) - 1ull); \
                    bfin = ((unsigned)(vmask >> k) & 1u) \
                         ^ ((unsigned)__builtin_popcountll(nmask & abv2) & 1u); \
                } else { \
                    bfin = b_start ^ ((unsigned)__builtin_popcountll(nmask) & 1u); \
                } \
                unsigned cur = excl; \
                SEQ(0, tq0) SEQ(1, tq1) SEQ(2, tq2) SEQ(3, tq3) \
                if (lane == owner) bmask = (bmask & ~(1u << slot)) | (bfin << slot); \
            } \
        } \
        mcur = mnext; \
    }

    unsigned mcur = s_mask[lane];   // row 0
    RUNCHUNK(0, any0, ac0, a0_0, a1_0, 64)
    RUNCHUNK(1, any1, ac1, a0_1, a1_1, 64)
    RUNCHUNK(2, any2, ac2, a0_2, a1_2, 64)
    RUNCHUNK(3, any3, ac3, a0_3, a1_3, 63)

#undef RUNCHUNK
#undef SEQ
#undef DOQ
#undef APPLY_B

#pragma unroll
    for (int q = 0; q < 4; ++q) {
        const int k = lane * 4 + q;
        const unsigned bq = (bmask >> q) & 1u;
        outb[k*28 + 8] = bq ? nj[q] : pj[q];
        outb[k*28 + 9] = bq ? pj[q] : nj[q];
    }
}

// ---------------------------------------------------------------------------
// Fallback (round-1 verified kernel) in case ws_size is too small.
// ---------------------------------------------------------------------------
__global__ __launch_bounds__(64)
void proposal_suppress_kernel(const float* __restrict__ pc, const float* __restrict__ ps,
                              const float* __restrict__ ph, const float* __restrict__ sem,
                              const float* __restrict__ av, float* __restrict__ out)
{
#pragma clang fp contract(off)
    const int b    = blockIdx.x;
    const int lane = threadIdx.x;

    __shared__ float s_p[KK], s_n[KK], s_d[KK][6], s_c[KK][3];

    const float* pcb  = pc  + (size_t)b * 3 * KK;
    const float* psb  = ps  + (size_t)b * 3 * KK;
    const float* phb  = ph  + (size_t)b * 2 * KK;
    const float* semb = sem + (size_t)b * (2 + NCLS) * KK;
    const float* avb  = av  + (size_t)b * KK * 3;
    float* outb       = out + (size_t)b * KK * 28;

    float pj[4], nj[4], dj[4][6], cj[4][3];
    unsigned Ljm = 0, Gjm = 0, bmask = 0;

#pragma unroll
    for (int q = 0; q < 4; ++q) {
        const int k = lane * 4 + q;
        const float c0 = avb[k*3+0] + pcb[0*KK + k];
        const float c1 = avb[k*3+1] + pcb[1*KK + k];
        const float c2 = avb[k*3+2] + pcb[2*KK + k];
        const float s0 = psb[0*KK + k], s1 = psb[1*KK + k], s2 = psb[2*KK + k];
        const float h0 = phb[0*KK + k], h1 = phb[1*KK + k];
        const float v0 = s0 * h1, v1 = s1, v2 = s2 * h1;
        float d[6];
        d[0] = (v0 + c0) - fabsf(s0); d[1] = (v0 + c0);
        d[2] = (v1 + c1) - fabsf(s1); d[3] = (v1 + c1);
        d[4] = (v2 + c2) - fabsf(s2); d[5] = (v2 + c2);
        const float p = semb[0*KK + k];
        const float n = semb[1*KK + k];
        cj[q][0] = c0; cj[q][1] = c1; cj[q][2] = c2;
#pragma unroll
        for (int m = 0; m < 6; ++m) dj[q][m] = d[m];
        pj[q] = p; nj[q] = n;
        if (p < n) Ljm |= 1u << q;
        if (n < p) Gjm |= 1u << q;
        s_p[k] = p; s_n[k] = n;
#pragma unroll
        for (int m = 0; m < 6; ++m) s_d[k][m] = d[m];
        s_c[k][0] = c0; s_c[k][1] = c1; s_c[k][2] = c2;
        outb[k*28 + 0] = c0; outb[k*28 + 1] = c1; outb[k*28 + 2] = c2;
        outb[k*28 + 3] = s0; outb[k*28 + 4] = s1; outb[k*28 + 5] = s2;
        outb[k*28 + 6] = h0; outb[k*28 + 7] = h1;
#pragma unroll
        for (int cc = 0; cc < NCLS; ++cc)
            outb[k*28 + 10 + cc] = semb[(2 + cc)*KK + k];
    }
    __syncthreads();

    const unsigned ID = 2u;
    for (int i = 0; i < KK - 1; ++i) {
        const float piv = s_p[i], niv = s_n[i];
        const float di0 = s_d[i][0], di1 = s_d[i][1], di2 = s_d[i][2];
        const float di3 = s_d[i][3], di4 = s_d[i][4], di5 = s_d[i][5];
        const float ci0 = s_c[i][0], ci1 = s_c[i][1], ci2 = s_c[i][2];
        const unsigned tA = (piv < niv ? 1u : 0u) | ((niv < piv ? 0u : 1u) << 1);
        const int owner = i >> 2, slot = i & 3;

        unsigned tq[4];
        unsigned Cq = 0, cc0m = 0, cc1m = 0;
        unsigned tl = ID;
#pragma unroll
        for (int q = 0; q < 4; ++q) {
            const int j = lane * 4 + q;
            unsigned t = ID;
            if (j > i) {
                const float dx = ci0 - cj[q][0];
                const float dy = ci1 - cj[q][1];
                const float dz = ci2 - cj[q][2];
                const float dist2 = dx*dx + dy*dy + dz*dz;
                if (dist2 < 9.0f) {
                    const bool case0 = (dj[q][0] < di0) & (dj[q][1] > di1)
                                     & (dj[q][2] < di2) & (dj[q][3] > di3)
                                     & (dj[q][4] < di4) & (dj[q][5] > di5);
                    const bool case1 = (dj[q][0] > di0) & (dj[q][1] < di1)
                                     & (dj[q][2] > di2) & (dj[q][3] < di3)
                                     & (dj[q][4] > di4) & (dj[q][5] < di5);
                    if (case0) {
                        t = tA;
                    } else if (case1) {
                        const unsigned bj = (bmask >> q) & 1u;
                        const unsigned nb = bj ? (((Gjm >> q) & 1u) ? 0u : 1u)
                                               : (((Ljm >> q) & 1u) ? 1u : 0u);
                        bmask = (bmask & ~(1u << q)) | (nb << q);
                    } else {
                        const bool ovx = ((dj[q][1] > di0) & (dj[q][1] < di1))
                                       | ((di1 > dj[q][0]) & (di1 < dj[q][1]));
                        const bool ovy = ((dj[q][3] > di2) & (dj[q][3] < di3))
                                       | ((di3 > dj[q][2]) & (di3 < dj[q][3]));
                        const bool ovz = ((dj[q][5] > di4) & (dj[q][5] < di5))
                                       | ((di5 > dj[q][4]) & (di5 < dj[q][5]));
                        if (ovx & ovy & ovz) {
                            const unsigned bj = (bmask >> q) & 1u;
                            const float sj = bj ? pj[q] : nj[q];
                            const unsigned c0b = (niv < sj) ? 1u : 0u;
                            const unsigned c1b = (piv < sj) ? 1u : 0u;
                            t = c0b | ((c1b ^ 1u) << 1u);
                            Cq |= 1u << q; cc0m |= c0b << q; cc1m |= c1b << q;
                        }
                    }
                }
            }
            tq[q] = t;
            tl = compose2(tl, t);
        }

        const unsigned long long any = __ballot((tl != ID) || (Cq != 0));
        if (any == 0ull) continue;

        const unsigned b_start = (((unsigned)__shfl((int)bmask, owner, 64)) >> slot) & 1u;

        unsigned incl = tl;
#pragma unroll
        for (int off = 1; off < 64; off <<= 1) {
            const unsigned other = (unsigned)__shfl_up((int)incl, (unsigned)off, 64);
            if (lane >= off) incl = compose2(other, incl);
        }
        const unsigned total = (unsigned)__shfl((int)incl, 63, 64);
        const unsigned upv   = (unsigned)__shfl_up((int)incl, 1u, 64);
        const unsigned excl  = (lane == 0) ? ID : upv;

        unsigned cur = (excl >> b_start) & 1u;
#pragma unroll
        for (int q = 0; q < 4; ++q) {
            if ((Cq >> q) & 1u) {
                const unsigned cond = cur ? ((cc1m >> q) & 1u) : ((cc0m >> q) & 1u);
                if (!cond) bmask ^= (1u << q);
            }
            cur = (tq[q] >> cur) & 1u;
        }
        if (lane == owner) {
            const unsigned nbi = (total >> b_start) & 1u;
            bmask = (bmask & ~(1u << slot)) | (nbi << slot);
        }
    }

#pragma unroll
    for (int q = 0; q < 4; ++q) {
        const int k = lane * 4 + q;
        const unsigned bq = (bmask >> q) & 1u;
        outb[k*28 + 8] = bq ? nj[q] : pj[q];
        outb[k*28 + 9] = bq ? pj[q] : nj[q];
    }
}

extern "C" void kernel_launch(void* const* d_in, const int* in_sizes, int n_in,
                              void* d_out, int out_size, void* d_ws, size_t ws_size,
                              hipStream_t stream) {
    const float* pc  = (const float*)d_in[0];
    const float* ps  = (const float*)d_in[1];
    const float* ph  = (const float*)d_in[2];
    const float* sem = (const float*)d_in[3];
    const float* av  = (const float*)d_in[4];
    float* out = (float*)d_out;
    const int B = in_sizes[0] / (3 * KK);

    const size_t need = (size_t)B * MASK_BYTES_PER_BATCH + (size_t)B * KK;
    if (ws_size >= need) {
        unsigned char* wm   = (unsigned char*)d_ws;
        unsigned char* wsum = wm + (size_t)B * MASK_BYTES_PER_BATCH;
        flags_kernel<<<dim3(B * 16), dim3(256), 0, stream>>>(pc, ps, ph, sem, av, wm, wsum, out);
        suppress3_kernel<<<dim3(B), dim3(64), 0, stream>>>(sem, wm, wsum, out);
    } else {
        proposal_suppress_kernel<<<dim3(B), dim3(64), 0, stream>>>(pc, ps, ph, sem, av, out);
    }
}

// Round 4
// 56.764 us; speedup vs baseline: 5.3005x; 1.1285x over previous
//
#include <hip/hip_runtime.h>

#define KK 256
#define NCLS 18
#define MASK_BYTES_PER_BATCH (KK * KK)   // 65536

typedef unsigned long long ull;

// Transition on a 1-bit state encoded as t = T(0) | (T(1)<<1).
// compose2(a,b) = "apply a, then b".  id=2, not=1, const0=0, const1=3.
__device__ __forceinline__ unsigned compose2(unsigned a, unsigned b) {
    unsigned r0 = (b >> (a & 1u)) & 1u;
    unsigned r1 = (b >> ((a >> 1) & 1u)) & 1u;
    return r0 | (r1 << 1u);
}

// Extract bit `bpos` of each of the 4 packed bytes in m -> 4-bit mask.
__device__ __forceinline__ unsigned ext4(unsigned m, int bpos) {
    unsigned x = (m >> bpos) & 0x01010101u;
    x |= x >> 7;
    x |= x >> 14;
    return x & 0xFu;
}

// ---------------------------------------------------------------------------
// Phase 1: fully parallel per-pair flag precompute + all pass-through outputs.
// code byte (i,j):  bit0=A, bit1=B, bit2=C,
//                   bit3=cond(0,0)=n_i<n_j  bit4=cond(1,0)=p_i<n_j
//                   bit5=cond(0,1)=n_i<p_j  bit6=cond(1,1)=p_i<p_j
// summary byte (i): bit0=row has any event, bit1=row has A or C (unused now),
//                   bit2=tA(0)=(p_i<n_i),   bit3=tA(1)=!(n_i<p_i)
// LDS layout: sdpn[k] = {d0..d5, p, n, pad} stride 9 words -> 2-way max.
// ---------------------------------------------------------------------------
__global__ __launch_bounds__(256)
void flags_kernel(const float* __restrict__ pc, const float* __restrict__ ps,
                  const float* __restrict__ ph, const float* __restrict__ sem,
                  const float* __restrict__ av,
                  unsigned char* __restrict__ ws_mask,
                  unsigned char* __restrict__ ws_sum,
                  float* __restrict__ out)
{
#pragma clang fp contract(off)
    const int blk = blockIdx.x;
    const int b   = blk >> 4;
    const int g   = blk & 15;
    const int tid = threadIdx.x;

    __shared__ float sdpn[KK][9];
    __shared__ float sc[KK][3];
    __shared__ unsigned rowsum[16];

    const float* pcb  = pc  + (size_t)b * 3 * KK;
    const float* psb  = ps  + (size_t)b * 3 * KK;
    const float* phb  = ph  + (size_t)b * 2 * KK;
    const float* semb = sem + (size_t)b * (2 + NCLS) * KK;
    const float* avb  = av  + (size_t)b * KK * 3;
    float* outb       = out + (size_t)b * KK * 28;

    {   // stage proposal `tid`'s derived data (identical float exprs to ref)
        const int k = tid;
        const float c0 = avb[k*3+0] + pcb[0*KK + k];
        const float c1 = avb[k*3+1] + pcb[1*KK + k];
        const float c2 = avb[k*3+2] + pcb[2*KK + k];
        const float s0 = psb[0*KK + k], s1 = psb[1*KK + k], s2 = psb[2*KK + k];
        const float h1 = phb[1*KK + k];
        const float v0 = s0 * h1, v1 = s1, v2 = s2 * h1;
        sdpn[k][0] = (v0 + c0) - fabsf(s0);
        sdpn[k][1] = (v0 + c0);
        sdpn[k][2] = (v1 + c1) - fabsf(s1);
        sdpn[k][3] = (v1 + c1);
        sdpn[k][4] = (v2 + c2) - fabsf(s2);
        sdpn[k][5] = (v2 + c2);
        sdpn[k][6] = semb[0*KK + k];
        sdpn[k][7] = semb[1*KK + k];
        sc[k][0] = c0; sc[k][1] = c1; sc[k][2] = c2;
    }
    if (tid < 16) rowsum[tid] = 0;
    __syncthreads();

    const int rl = tid >> 4;          // local row 0..15
    const int i  = g * 16 + rl;       // global row
    const int j0 = (tid & 15) * 16;   // 16 j's per thread

    const float piv = sdpn[i][6], niv = sdpn[i][7];
    const float di0 = sdpn[i][0], di1 = sdpn[i][1], di2 = sdpn[i][2];
    const float di3 = sdpn[i][3], di4 = sdpn[i][4], di5 = sdpn[i][5];
    const float ci0 = sc[i][0], ci1 = sc[i][1], ci2 = sc[i][2];

    unsigned codes[16];
    unsigned anyf = 0, acf = 0;
#pragma unroll
    for (int t = 0; t < 16; ++t) {
        const int j = j0 + t;
        unsigned code = 0;
        if (j > i) {
            const float dx = ci0 - sc[j][0];
            const float dy = ci1 - sc[j][1];
            const float dz = ci2 - sc[j][2];
            const float dist2 = dx*dx + dy*dy + dz*dz;
            if (dist2 < 9.0f) {
                const float e0 = sdpn[j][0], e1 = sdpn[j][1], e2 = sdpn[j][2];
                const float e3 = sdpn[j][3], e4 = sdpn[j][4], e5 = sdpn[j][5];
                const bool case0 = (e0 < di0) & (e1 > di1) & (e2 < di2)
                                 & (e3 > di3) & (e4 < di4) & (e5 > di5);
                const bool case1 = (e0 > di0) & (e1 < di1) & (e2 > di2)
                                 & (e3 < di3) & (e4 > di4) & (e5 < di5);
                if (case0) {
                    code = 1u;
                } else if (case1) {
                    code = 2u;
                } else {
                    const bool ovx = ((e1 > di0) & (e1 < di1)) | ((di1 > e0) & (di1 < e1));
                    const bool ovy = ((e3 > di2) & (e3 < di3)) | ((di3 > e2) & (di3 < e3));
                    const bool ovz = ((e5 > di4) & (e5 < di5)) | ((di5 > e4) & (di5 < e5));
                    if (ovx & ovy & ovz) {
                        const float pj = sdpn[j][6], nj = sdpn[j][7];
                        const unsigned c00 = (niv < nj) ? 1u : 0u;
                        const unsigned c10 = (piv < nj) ? 1u : 0u;
                        const unsigned c01 = (niv < pj) ? 1u : 0u;
                        const unsigned c11 = (piv < pj) ? 1u : 0u;
                        code = 4u | (c00<<3) | (c10<<4) | (c01<<5) | (c11<<6);
                    }
                }
            }
        }
        codes[t] = code;
        anyf |= code;
        acf  |= code & 5u;
    }

    // pack 16 codes -> 4 words -> one 16B store
    uint4 w;
    w.x = codes[0]  | (codes[1]<<8)  | (codes[2]<<16)  | (codes[3]<<24);
    w.y = codes[4]  | (codes[5]<<8)  | (codes[6]<<16)  | (codes[7]<<24);
    w.z = codes[8]  | (codes[9]<<8)  | (codes[10]<<16) | (codes[11]<<24);
    w.w = codes[12] | (codes[13]<<8) | (codes[14]<<16) | (codes[15]<<24);
    *(uint4*)(ws_mask + (size_t)b * MASK_BYTES_PER_BATCH + i * KK + j0) = w;

    const unsigned f = (anyf ? 1u : 0u) | (acf ? 2u : 0u);
    if (f) atomicOr(&rowsum[rl], f);

    // pass-through outputs for this block's k-slice [g*16, g*16+16)
    for (int s = tid; s < 16 * 28; s += 256) {
        const int kk = g * 16 + (s / 28);
        const int c  = s % 28;
        if (c == 8 || c == 9) continue;      // scores written by phase 2
        float val;
        if (c < 3)       val = sc[kk][c];
        else if (c < 6)  val = psb[(c - 3) * KK + kk];
        else if (c < 8)  val = phb[(c - 6) * KK + kk];
        else             val = semb[(c - 8) * KK + kk];
        outb[(size_t)kk * 28 + c] = val;
    }

    __syncthreads();
    if (tid < 16) {
        const int i2 = g * 16 + tid;
        const unsigned tab = ((sdpn[i2][6] < sdpn[i2][7]) ? 4u : 0u)
                           | ((sdpn[i2][7] < sdpn[i2][6]) ? 0u : 8u);
        ws_sum[b * KK + i2] = (unsigned char)(rowsum[tid] | tab);
    }
}

// ---------------------------------------------------------------------------
// Phase 2: one wave per batch. Bit-parallel row body, dual-entry speculative
// side effects, lowbit-in-reversed-domain segmented scan. ~30-op dep chain.
// ---------------------------------------------------------------------------
__global__ __launch_bounds__(64)
void suppress4_kernel(const float* __restrict__ sem,
                      const unsigned char* __restrict__ ws_mask,
                      const unsigned char* __restrict__ ws_sum,
                      float* __restrict__ out)
{
    const int b    = blockIdx.x;
    const int lane = threadIdx.x;

    __shared__ unsigned s_mask[KK * 64];   // 64 KB: linear copy of batch codes

    const float* semb = sem + (size_t)b * (2 + NCLS) * KK;
    float* outb       = out + (size_t)b * KK * 28;

    // stage codes: global -> LDS, 8 x 16B in flight per sweep group
    const uint4* gm = (const uint4*)(ws_mask + (size_t)b * MASK_BYTES_PER_BATCH);
    uint4* sm4 = (uint4*)s_mask;
    for (int so = 0; so < 64; so += 8) {
        uint4 v[8];
#pragma unroll
        for (int t = 0; t < 8; ++t) v[t] = gm[(so + t) * 64 + lane];
#pragma unroll
        for (int t = 0; t < 8; ++t) sm4[(so + t) * 64 + lane] = v[t];
    }

    float pj[4], nj[4];
    unsigned Ljm = 0, Gjm = 0, bmask = 0;
#pragma unroll
    for (int q = 0; q < 4; ++q) {
        const int k = lane * 4 + q;
        const float p = semb[0*KK + k];
        const float n = semb[1*KK + k];
        pj[q] = p; nj[q] = n;
        if (p < n) Ljm |= 1u << q;
        if (n < p) Gjm |= 1u << q;
    }

    // summary bytes -> uniform bitmaps via ballots
    const unsigned char* sb = ws_sum + b * KK;
    const unsigned sb0 = sb[lane], sb1 = sb[64 + lane],
                   sb2 = sb[128 + lane], sb3 = sb[192 + lane];
    const ull any0 = __ballot(sb0 & 1u), a0_0 = __ballot(sb0 & 4u), a1_0 = __ballot(sb0 & 8u);
    const ull any1 = __ballot(sb1 & 1u), a0_1 = __ballot(sb1 & 4u), a1_1 = __ballot(sb1 & 8u);
    const ull any2 = __ballot(sb2 & 1u), a0_2 = __ballot(sb2 & 4u), a1_2 = __ballot(sb2 & 8u);
    const ull any3 = __ballot(sb3 & 1u), a0_3 = __ballot(sb3 & 4u), a1_3 = __ballot(sb3 & 8u);

    __syncthreads();   // staging complete

    const ull below  = (1ull << lane) - 1ull;
    const ull belowR = __builtin_bitreverse64(below);

#define ROWBODY(i, bb, A0, A1) { \
        const unsigned m = mcur; \
        const int owner = (i) >> 2, slot = (i) & 3; \
        const unsigned tA0x = ((unsigned)(((A0) >> (bb)) & 1ull)) * 0xFu; \
        const unsigned tA1x = ((unsigned)(((A1) >> (bb)) & 1ull)) * 0xFu; \
        /* static extracts (off-chain, pure ILP) */ \
        const unsigned isA4 = ext4(m, 0), isB4 = ext4(m, 1), isC4 = ext4(m, 2); \
        const unsigned e3 = ext4(m, 3), e4 = ext4(m, 4); \
        const unsigned e5 = ext4(m, 5), e6 = ext4(m, 6); \
        /* b_start ballot: parallel with the T-chain */ \
        const ull bsb = __ballot((bmask >> slot) & 1u); \
        const unsigned b_start = (unsigned)((bsb >> owner) & 1ull); \
        /* chain: bmask -> selects -> transitions */ \
        const unsigned bm  = bmask; \
        const unsigned c0v = (e3 & ~bm) | (e5 & bm); \
        const unsigned c1v = (e4 & ~bm) | (e6 & bm); \
        const unsigned nbv = (Ljm & ~bm) | (~Gjm & bm); \
        const unsigned bmB = (bm & ~isB4) | (nbv & isB4); \
        const unsigned T0  = (isA4 & tA0x) | (isC4 & c0v); \
        const unsigned T1  = (isA4 & tA1x) | (isC4 & ~c1v & 0xFu) | (~(isA4 | isC4) & 0xFu); \
        const unsigned t0 = (T0 & 1u)        | ((T1 & 1u) << 1); \
        const unsigned t1 = ((T0 >> 1) & 1u) | (((T1 >> 1) & 1u) << 1); \
        const unsigned t2 = ((T0 >> 2) & 1u) | (((T1 >> 2) & 1u) << 1); \
        const unsigned t3 = ((T0 >> 3) & 1u) | (((T1 >> 3) & 1u) << 1); \
        const unsigned c01 = compose2(t0, t1); \
        const unsigned c23 = compose2(t2, t3); \
        const unsigned tl  = compose2(c01, c23); \
        const unsigned p3  = compose2(c01, t2); \
        /* prefix states for both entries (bit q = state BEFORE step q) */ \
        const unsigned av0 = ((t0 & 1u) << 1) | ((c01 & 1u) << 2) | ((p3 & 1u) << 3); \
        const unsigned av1 = 1u | (((t0 >> 1) & 1u) << 1) | (((c01 >> 1) & 1u) << 2) \
                                | (((p3 >> 1) & 1u) << 3); \
        /* speculative C side-effect flips for both entries */ \
        const unsigned cv0 = (av0 & c1v) | (~av0 & c0v); \
        const unsigned cv1 = (av1 & c1v) | (~av1 & c0v); \
        const unsigned f0  = isC4 & ~cv0 & 0xFu; \
        const unsigned f1  = isC4 & ~cv1 & 0xFu; \
        /* classify tl across lanes */ \
        const ull b0m = __ballot(tl & 1u); \
        const ull b1m = __ballot((tl >> 1) & 1u); \
        const ull nm  = b0m & ~b1m; \
        const ull cm  = ~(b0m ^ b1m); \
        const ull cmr = __builtin_bitreverse64(cm); \
        const ull nmr = __builtin_bitreverse64(nm); \
        const ull Wr  = __builtin_bitreverse64(b0m); \
        /* per-lane entry value (segmented scan via lowest-bit in rev domain) */ \
        const ull cbr = cmr & belowR; \
        const ull lb  = cbr & (0ull - cbr); \
        const unsigned vK  = ((Wr & lb) != 0ull) ? 1u : 0u; \
        const ull betw = belowR & (lb - 1ull); \
        const unsigned par = (unsigned)__builtin_popcountll(nmr & betw) & 1u; \
        const unsigned base = (cbr != 0ull) ? vK : b_start; \
        const unsigned excl = base ^ par; \
        /* uniform final b_i (pure SALU) */ \
        const ull lbA = cmr & (0ull - cmr); \
        const unsigned vKA  = ((Wr & lbA) != 0ull) ? 1u : 0u; \
        const unsigned parA = (unsigned)__builtin_popcountll(nmr & (lbA - 1ull)) & 1u; \
        const unsigned bfin = ((cmr != 0ull) ? vKA : b_start) ^ parA; \
        /* commit */ \
        const unsigned flips = excl ? f1 : f0; \
        unsigned nbm = bmB ^ flips; \
        if (lane == owner) nbm = (nbm & ~(1u << slot)) | (bfin << slot); \
        bmask = nbm; }

#define RUNCHUNK(W, ANY, A0, A1, NROWS) \
    for (int bb = 0; bb < (NROWS); ++bb) { \
        const int i = ((W) << 6) + bb; \
        const unsigned mnext = s_mask[(i + 1) * 64 + lane]; \
        if (((ANY) >> bb) & 1ull) ROWBODY(i, bb, A0, A1) \
        mcur = mnext; \
    }

    unsigned mcur = s_mask[lane];   // row 0
    RUNCHUNK(0, any0, a0_0, a1_0, 64)
    RUNCHUNK(1, any1, a0_1, a1_1, 64)
    RUNCHUNK(2, any2, a0_2, a1_2, 64)
    RUNCHUNK(3, any3, a0_3, a1_3, 63)

#undef RUNCHUNK
#undef ROWBODY

#pragma unroll
    for (int q = 0; q < 4; ++q) {
        const int k = lane * 4 + q;
        const unsigned bq = (bmask >> q) & 1u;
        outb[k*28 + 8] = bq ? nj[q] : pj[q];
        outb[k*28 + 9] = bq ? pj[q] : nj[q];
    }
}

// ---------------------------------------------------------------------------
// Fallback (round-1 verified kernel) in case ws_size is too small.
// ---------------------------------------------------------------------------
__global__ __launch_bounds__(64)
void proposal_suppress_kernel(const float* __restrict__ pc, const float* __restrict__ ps,
                              const float* __restrict__ ph, const float* __restrict__ sem,
                              const float* __restrict__ av, float* __restrict__ out)
{
#pragma clang fp contract(off)
    const int b    = blockIdx.x;
    const int lane = threadIdx.x;

    __shared__ float s_p[KK], s_n[KK], s_d[KK][6], s_c[KK][3];

    const float* pcb  = pc  + (size_t)b * 3 * KK;
    const float* psb  = ps  + (size_t)b * 3 * KK;
    const float* phb  = ph  + (size_t)b * 2 * KK;
    const float* semb = sem + (size_t)b * (2 + NCLS) * KK;
    const float* avb  = av  + (size_t)b * KK * 3;
    float* outb       = out + (size_t)b * KK * 28;

    float pj[4], nj[4], dj[4][6], cj[4][3];
    unsigned Ljm = 0, Gjm = 0, bmask = 0;

#pragma unroll
    for (int q = 0; q < 4; ++q) {
        const int k = lane * 4 + q;
        const float c0 = avb[k*3+0] + pcb[0*KK + k];
        const float c1 = avb[k*3+1] + pcb[1*KK + k];
        const float c2 = avb[k*3+2] + pcb[2*KK + k];
        const float s0 = psb[0*KK + k], s1 = psb[1*KK + k], s2 = psb[2*KK + k];
        const float h0 = phb[0*KK + k], h1 = phb[1*KK + k];
        const float v0 = s0 * h1, v1 = s1, v2 = s2 * h1;
        float d[6];
        d[0] = (v0 + c0) - fabsf(s0); d[1] = (v0 + c0);
        d[2] = (v1 + c1) - fabsf(s1); d[3] = (v1 + c1);
        d[4] = (v2 + c2) - fabsf(s2); d[5] = (v2 + c2);
        const float p = semb[0*KK + k];
        const float n = semb[1*KK + k];
        cj[q][0] = c0; cj[q][1] = c1; cj[q][2] = c2;
#pragma unroll
        for (int m = 0; m < 6; ++m) dj[q][m] = d[m];
        pj[q] = p; nj[q] = n;
        if (p < n) Ljm |= 1u << q;
        if (n < p) Gjm |= 1u << q;
        s_p[k] = p; s_n[k] = n;
#pragma unroll
        for (int m = 0; m < 6; ++m) s_d[k][m] = d[m];
        s_c[k][0] = c0; s_c[k][1] = c1; s_c[k][2] = c2;
        outb[k*28 + 0] = c0; outb[k*28 + 1] = c1; outb[k*28 + 2] = c2;
        outb[k*28 + 3] = s0; outb[k*28 + 4] = s1; outb[k*28 + 5] = s2;
        outb[k*28 + 6] = h0; outb[k*28 + 7] = h1;
#pragma unroll
        for (int cc = 0; cc < NCLS; ++cc)
            outb[k*28 + 10 + cc] = semb[(2 + cc)*KK + k];
    }
    __syncthreads();

    const unsigned ID = 2u;
    for (int i = 0; i < KK - 1; ++i) {
        const float piv = s_p[i], niv = s_n[i];
        const float di0 = s_d[i][0], di1 = s_d[i][1], di2 = s_d[i][2];
        const float di3 = s_d[i][3], di4 = s_d[i][4], di5 = s_d[i][5];
        const float ci0 = s_c[i][0], ci1 = s_c[i][1], ci2 = s_c[i][2];
        const unsigned tA = (piv < niv ? 1u : 0u) | ((niv < piv ? 0u : 1u) << 1);
        const int owner = i >> 2, slot = i & 3;

        unsigned tq[4];
        unsigned Cq = 0, cc0m = 0, cc1m = 0;
        unsigned tl = ID;
#pragma unroll
        for (int q = 0; q < 4; ++q) {
            const int j = lane * 4 + q;
            unsigned t = ID;
            if (j > i) {
                const float dx = ci0 - cj[q][0];
                const float dy = ci1 - cj[q][1];
                const float dz = ci2 - cj[q][2];
                const float dist2 = dx*dx + dy*dy + dz*dz;
                if (dist2 < 9.0f) {
                    const bool case0 = (dj[q][0] < di0) & (dj[q][1] > di1)
                                     & (dj[q][2] < di2) & (dj[q][3] > di3)
                                     & (dj[q][4] < di4) & (dj[q][5] > di5);
                    const bool case1 = (dj[q][0] > di0) & (dj[q][1] < di1)
                                     & (dj[q][2] > di2) & (dj[q][3] < di3)
                                     & (dj[q][4] > di4) & (dj[q][5] < di5);
                    if (case0) {
                        t = tA;
                    } else if (case1) {
                        const unsigned bj = (bmask >> q) & 1u;
                        const unsigned nb = bj ? (((Gjm >> q) & 1u) ? 0u : 1u)
                                               : (((Ljm >> q) & 1u) ? 1u : 0u);
                        bmask = (bmask & ~(1u << q)) | (nb << q);
                    } else {
                        const bool ovx = ((dj[q][1] > di0) & (dj[q][1] < di1))
                                       | ((di1 > dj[q][0]) & (di1 < dj[q][1]));
                        const bool ovy = ((dj[q][3] > di2) & (dj[q][3] < di3))
                                       | ((di3 > dj[q][2]) & (di3 < dj[q][3]));
                        const bool ovz = ((dj[q][5] > di4) & (dj[q][5] < di5))
                                       | ((di5 > dj[q][4]) & (di5 < dj[q][5]));
                        if (ovx & ovy & ovz) {
                            const unsigned bj = (bmask >> q) & 1u;
                            const float sj = bj ? pj[q] : nj[q];
                            const unsigned c0b = (niv < sj) ? 1u : 0u;
                            const unsigned c1b = (piv < sj) ? 1u : 0u;
                            t = c0b | ((c1b ^ 1u) << 1u);
                            Cq |= 1u << q; cc0m |= c0b << q; cc1m |= c1b << q;
                        }
                    }
                }
            }
            tq[q] = t;
            tl = compose2(tl, t);
        }

        const ull any = __ballot((tl != ID) || (Cq != 0));
        if (any == 0ull) continue;

        const unsigned b_start = (((unsigned)__shfl((int)bmask, owner, 64)) >> slot) & 1u;

        unsigned incl = tl;
#pragma unroll
        for (int off = 1; off < 64; off <<= 1) {
            const unsigned other = (unsigned)__shfl_up((int)incl, (unsigned)off, 64);
            if (lane >= off) incl = compose2(other, incl);
        }
        const unsigned total = (unsigned)__shfl((int)incl, 63, 64);
        const unsigned upv   = (unsigned)__shfl_up((int)incl, 1u, 64);
        const unsigned excl  = (lane == 0) ? ID : upv;

        unsigned cur = (excl >> b_start) & 1u;
#pragma unroll
        for (int q = 0; q < 4; ++q) {
            if ((Cq >> q) & 1u) {
                const unsigned cond = cur ? ((cc1m >> q) & 1u) : ((cc0m >> q) & 1u);
                if (!cond) bmask ^= (1u << q);
            }
            cur = (tq[q] >> cur) & 1u;
        }
        if (lane == owner) {
            const unsigned nbi = (total >> b_start) & 1u;
            bmask = (bmask & ~(1u << slot)) | (nbi << slot);
        }
    }

#pragma unroll
    for (int q = 0; q < 4; ++q) {
        const int k = lane * 4 + q;
        const unsigned bq = (bmask >> q) & 1u;
        outb[k*28 + 8] = bq ? nj[q] : pj[q];
        outb[k*28 + 9] = bq ? pj[q] : nj[q];
    }
}

extern "C" void kernel_launch(void* const* d_in, const int* in_sizes, int n_in,
                              void* d_out, int out_size, void* d_ws, size_t ws_size,
                              hipStream_t stream) {
    const float* pc  = (const float*)d_in[0];
    const float* ps  = (const float*)d_in[1];
    const float* ph  = (const float*)d_in[2];
    const float* sem = (const float*)d_in[3];
    const float* av  = (const float*)d_in[4];
    float* out = (float*)d_out;
    const int B = in_sizes[0] / (3 * KK);

    const size_t need = (size_t)B * MASK_BYTES_PER_BATCH + (size_t)B * KK;
    if (ws_size >= need) {
        unsigned char* wm   = (unsigned char*)d_ws;
        unsigned char* wsum = wm + (size_t)B * MASK_BYTES_PER_BATCH;
        flags_kernel<<<dim3(B * 16), dim3(256), 0, stream>>>(pc, ps, ph, sem, av, wm, wsum, out);
        suppress4_kernel<<<dim3(B), dim3(64), 0, stream>>>(sem, wm, wsum, out);
    } else {
        proposal_suppress_kernel<<<dim3(B), dim3(64), 0, stream>>>(pc, ps, ph, sem, av, out);
    }
}